// Round 16
// baseline (408.102 us; speedup 1.0000x reference)
//
#include <hip/hip_runtime.h>

typedef __attribute__((ext_vector_type(8))) short s16x8;
typedef __attribute__((ext_vector_type(8))) unsigned short u16x8;
typedef __attribute__((ext_vector_type(4))) float f32x4;

#define LN_EPS 1e-5f

__device__ inline float bf2f(unsigned short u) {
    union { unsigned int i; float f; } x; x.i = ((unsigned int)u) << 16; return x.f;
}
__device__ inline unsigned short f2bf(float f) {
    unsigned int u = __builtin_bit_cast(unsigned int, f);
    u += 0x7FFFu + ((u >> 16) & 1u);
    return (unsigned short)(u >> 16);
}
__device__ inline unsigned int cvt_pk_bf16(float lo, float hi) {
    unsigned int r;
    asm("v_cvt_pk_bf16_f32 %0, %1, %2" : "=v"(r) : "v"(lo), "v"(hi));
    return r;
}
typedef __attribute__((address_space(1))) const unsigned int as1_u32;
typedef __attribute__((address_space(3))) unsigned int as3_u32;
__device__ inline void gl2lds16(const void* g, void* l) {
    __builtin_amdgcn_global_load_lds((as1_u32*)g, (as3_u32*)l, 16, 0, 0);
}

__device__ inline u16x8 cvt8(float4 a, float4 b) {
    union { unsigned int u[4]; u16x8 v; } r;
    r.u[0] = cvt_pk_bf16(a.x, a.y);
    r.u[1] = cvt_pk_bf16(a.z, a.w);
    r.u[2] = cvt_pk_bf16(b.x, b.y);
    r.u[3] = cvt_pk_bf16(b.z, b.w);
    return r.v;
}

// Burst-8 f32 -> bf16 stream: 16 global_load_dwordx4 in flight per thread.
__device__ inline void cvt_stream(const float* __restrict__ src,
                                  unsigned short* __restrict__ dst,
                                  int n8, int lb, int nb, int tid)
{
    int i = lb * 256 + tid;
    const int stride = nb * 256;
    for (; i + 7 * stride < n8; i += 8 * stride) {
        float4 a[8], b[8];
#pragma unroll
        for (int j = 0; j < 8; ++j) {
            a[j] = ((const float4*)src)[2 * (i + j * stride)];
            b[j] = ((const float4*)src)[2 * (i + j * stride) + 1];
        }
#pragma unroll
        for (int j = 0; j < 8; ++j)
            ((u16x8*)dst)[i + j * stride] = cvt8(a[j], b[j]);
    }
    for (; i < n8; i += stride) {
        const float4 a = ((const float4*)src)[2 * i];
        const float4 b = ((const float4*)src)[2 * i + 1];
        ((u16x8*)dst)[i] = cvt8(a, b);
    }
}

// ---------------------------------------------------------------------------
// prep: embed (blocks 0..255) + cvt W1 + small-weight cvts.
// launch_bounds(256,2): VGPR cap 256 so the burst-8 actually allocates
// (previous default capped at 32 VGPR -> loads serialized, 2.2 TB/s).
// ---------------------------------------------------------------------------
__global__ __launch_bounds__(256, 2) void prep_kernel(
    const int* __restrict__ x, const float* __restrict__ emb,
    unsigned short* __restrict__ e,
    const float* __restrict__ w1, unsigned short* __restrict__ w1b,
    const float* __restrict__ ipw, unsigned short* __restrict__ ipwb,
    const float* __restrict__ opw, unsigned short* __restrict__ opwb,
    const float* __restrict__ dw1, unsigned short* __restrict__ dw1b,
    const float* __restrict__ dw2, unsigned short* __restrict__ dw2b)
{
    const int tid = threadIdx.x;
    int b = blockIdx.x;
    if (b < 256) {
        __shared__ int xs[128];
        if (tid < 128) xs[tid] = x[b * 128 + tid];
        __syncthreads();
        float s0 = 0.f, s1 = 0.f;
#pragma unroll 1
        for (int i = 0; i < 128; i += 8) {
            float va[8], vb[8];
#pragma unroll
            for (int j = 0; j < 8; ++j) {
                const float* r = emb + (size_t)xs[i + j] * 512;
                va[j] = r[tid];
                vb[j] = r[tid + 256];
            }
#pragma unroll
            for (int j = 0; j < 8; ++j) { s0 += va[j]; s1 += vb[j]; }
        }
        e[(size_t)b * 512 + tid] = f2bf(s0 * (1.f / 128.f));
        e[(size_t)b * 512 + tid + 256] = f2bf(s1 * (1.f / 128.f));
        return;
    }
    b -= 256;
    if (b < 2048) { cvt_stream(w1, w1b, 150 * 512 * 512 / 8, b, 2048, tid); return; }
    b -= 2048;
    if (b < 384) { cvt_stream(ipw, ipwb, 1536 * 512 / 8, b, 384, tid); return; }
    b -= 384;
    if (b < 128) { cvt_stream(opw, opwb, 512 * 512 / 8, b, 128, tid); return; }
    b -= 128;
    if (b < 64) { cvt_stream(dw1, dw1b, 256 * 512 / 8, b, 64, tid); return; }
    b -= 64;
    cvt_stream(dw2, dw2b, 10000 * 256 / 8, b, 1280, tid);
}
#define PREP_BLOCKS (256 + 2048 + 384 + 128 + 64 + 1280)

// ---------------------------------------------------------------------------
// BK=64 2-phase all-bf16 GEMM (m97 geometry, proven __syncthreads ping-pong):
//   C[z] = A[z](bf16) @ Wb[z](bf16)^T (+bias_scale*bias1+bias2)(+ReLU)
// 256 thr = 4 waves (2x2); tile 128x128; BK=64 (128B rows). Per buffer:
// A 16KB + B 16KB, staged via global_load_lds w=16 with full source XOR
// chunk^(row&7) (128B pitch = 32 banks, swizzle mandatory); read chunk
// (kk*4+ks)^(row&7). LDS 64KB -> 2 blocks/CU (launch_bounds 256,2).
// 32 MFMA per barrier-pair (2x the BK=32 version). Optional fused cvt tail.
// M multiple of 128; bf16-out N multiple of 128; f32-out N col-guarded.
// ---------------------------------------------------------------------------
template<int K, bool RELU, bool F32OUT>
__global__ __launch_bounds__(256, 2) void gemm_bf_kernel(
    const unsigned short* __restrict__ A,
    const unsigned short* __restrict__ Wb,
    const float* __restrict__ bias1,
    const float* __restrict__ bias2,
    float bias_scale,
    void* __restrict__ Cv,
    int N, int gx, int gy, int ngemm,
    size_t strideA_mode, size_t lda,
    size_t strideW_mode, size_t strideB_mode,
    size_t strideC_mode, size_t ldc,
    const float* __restrict__ cvt_src, unsigned short* __restrict__ cvt_dst,
    int cvt_n8)
{
    constexpr int NSTEP = K / 64;   // 8 for K=512, 4 for K=256 (both even)
    const int tid = threadIdx.x;
    const int wgid = blockIdx.x;

    if (wgid >= ngemm) {
        cvt_stream(cvt_src, cvt_dst, cvt_n8, wgid - ngemm, gridDim.x - ngemm, tid);
        return;
    }

    const int q8 = ngemm >> 3, r8 = ngemm & 7;
    const int xcd = wgid & 7, sub = wgid >> 3;
    int p = (xcd < r8 ? xcd * (q8 + 1) : r8 * (q8 + 1) + (xcd - r8) * q8) + sub;
    const int bx = p % gx; p /= gx;
    const int by = p % gy;
    const int bz = p / gy;
    const int n0 = bx * 128, r0 = by * 128;

    __shared__ __align__(16) unsigned char lds[2][32768];  // [A 16K | B 16K]

    const int lane = tid & 63, wid = tid >> 6;
    const int fr = lane & 15, ks = lane >> 4;
    const int wr = (wid >> 1) * 64, wc = (wid & 1) * 64;

    // staging: 4 insts each for A and B; inst I = wid*256 + j*64 + lane
    // row = I>>3 (0..127), phys chunk = I&7, source chunk = (I&7)^(row&7)
    const unsigned char* Aslab = (const unsigned char*)(A + (size_t)bz * strideA_mode);
    const unsigned char* Wslab = (const unsigned char*)(Wb + (size_t)bz * strideW_mode);
    const unsigned char* aSrc[4];
    const unsigned char* bSrc[4];
#pragma unroll
    for (int j = 0; j < 4; ++j) {
        const int I = wid * 256 + j * 64 + lane;
        const int row = I >> 3;
        const int sc = (I & 7) ^ (row & 7);
        aSrc[j] = Aslab + (size_t)(r0 + row) * lda * 2 + sc * 16;
        const int growb = min(n0 + row, N - 1);
        bSrc[j] = Wslab + (size_t)growb * K * 2 + sc * 16;
    }

    f32x4 acc[4][4];
#pragma unroll
    for (int i = 0; i < 4; ++i)
#pragma unroll
        for (int j = 0; j < 4; ++j)
#pragma unroll
            for (int r = 0; r < 4; ++r) acc[i][j][r] = 0.f;

    auto stage = [&](int buf, int t) {
#pragma unroll
        for (int j = 0; j < 4; ++j)
            gl2lds16(aSrc[j] + (size_t)t * 128, &lds[buf][(wid * 4 + j) * 1024]);
#pragma unroll
        for (int j = 0; j < 4; ++j)
            gl2lds16(bSrc[j] + (size_t)t * 128, &lds[buf][16384 + (wid * 4 + j) * 1024]);
    };

    auto compute = [&](int buf) {
        const unsigned char* Ab = &lds[buf][0];
        const unsigned char* Bb = &lds[buf][16384];
#pragma unroll
        for (int kk = 0; kk < 2; ++kk) {
            s16x8 af[4], bfr[4];
#pragma unroll
            for (int mi = 0; mi < 4; ++mi) {
                const int row = wr + mi * 16 + fr;
                af[mi] = *(const s16x8*)(Ab + row * 128 + (((kk * 4 + ks) ^ (row & 7)) << 4));
            }
#pragma unroll
            for (int ni = 0; ni < 4; ++ni) {
                const int row = wc + ni * 16 + fr;
                bfr[ni] = *(const s16x8*)(Bb + row * 128 + (((kk * 4 + ks) ^ (row & 7)) << 4));
            }
#pragma unroll
            for (int mi = 0; mi < 4; ++mi)
#pragma unroll
                for (int ni = 0; ni < 4; ++ni)
                    acc[mi][ni] = __builtin_amdgcn_mfma_f32_16x16x32_bf16(af[mi], bfr[ni], acc[mi][ni], 0, 0, 0);
        }
    };

    stage(0, 0);
    __syncthreads();

    for (int t = 0; t < NSTEP; t += 2) {
        stage(1, t + 1);
        compute(0);
        __syncthreads();
        if (t + 2 < NSTEP) stage(0, t + 2);
        compute(1);
        __syncthreads();
    }

    if (!F32OUT) {
        unsigned short* Cl = (unsigned short*)&lds[0][0];   // 128x128 bf16 = 32KB
#pragma unroll
        for (int ni = 0; ni < 4; ++ni) {
            const int col = n0 + wc + ni * 16 + fr;
            float bsum = 0.f;
            if (bias1) bsum += bias_scale * bias1[(size_t)bz * strideB_mode + col];
            if (bias2) bsum += bias2[(size_t)bz * strideB_mode + col];
#pragma unroll
            for (int mi = 0; mi < 4; ++mi)
#pragma unroll
                for (int r = 0; r < 4; ++r) {
                    float v = acc[mi][ni][r] + bsum;
                    if (RELU) v = fmaxf(v, 0.f);
                    Cl[(wr + mi * 16 + ks * 4 + r) * 128 + wc + ni * 16 + fr] = f2bf(v);
                }
        }
        __syncthreads();
        unsigned short* Cg = (unsigned short*)Cv + (size_t)bz * strideC_mode;
#pragma unroll
        for (int it = 0; it < 8; ++it) {
            const int c = it * 256 + tid;
            const int row = c >> 4, ch = c & 15;
            u16x8 v = *(const u16x8*)(&Cl[row * 128 + ch * 8]);
            *(u16x8*)(Cg + (size_t)(r0 + row) * ldc + n0 + ch * 8) = v;
        }
    } else {
#pragma unroll
        for (int ni = 0; ni < 4; ++ni) {
            const int col = n0 + wc + ni * 16 + fr;
            if (col < N) {
                float bsum = 0.f;
                if (bias1) bsum += bias_scale * bias1[(size_t)bz * strideB_mode + col];
                if (bias2) bsum += bias2[(size_t)bz * strideB_mode + col];
#pragma unroll
                for (int mi = 0; mi < 4; ++mi)
#pragma unroll
                    for (int r = 0; r < 4; ++r) {
                        const int row = r0 + wr + mi * 16 + ks * 4 + r;
                        float v = acc[mi][ni][r] + bsum;
                        if (RELU) v = fmaxf(v, 0.f);
                        ((float*)Cv)[(size_t)bz * strideC_mode + (size_t)row * ldc + col] = v;
                    }
            }
        }
    }
}

// ---------------------------------------------------------------------------
// Row LayerNorm over D=512 (+opt ReLU), gamma/beta f32, m = row % M.
// ---------------------------------------------------------------------------
template<bool RELU>
__global__ __launch_bounds__(256) void ln_kernel(
    const unsigned short* __restrict__ X,
    const float* __restrict__ G,
    const float* __restrict__ Bt,
    unsigned short* __restrict__ Y,
    int M)
{
    const int row = blockIdx.x;
    const int m = row % M;
    const unsigned short* xr = X + (size_t)row * 512;
    unsigned short* yr = Y + (size_t)row * 512;
    const int tid = threadIdx.x;
    const float x0 = bf2f(xr[tid]), x1 = bf2f(xr[tid + 256]);
    float s = x0 + x1, q = x0 * x0 + x1 * x1;
#pragma unroll
    for (int off = 32; off; off >>= 1) {
        s += __shfl_xor(s, off);
        q += __shfl_xor(q, off);
    }
    __shared__ float red[4][2];
    const int wid = tid >> 6, lane = tid & 63;
    if (lane == 0) { red[wid][0] = s; red[wid][1] = q; }
    __syncthreads();
    s = red[0][0] + red[1][0] + red[2][0] + red[3][0];
    q = red[0][1] + red[1][1] + red[2][1] + red[3][1];
    const float mu = s * (1.f / 512.f);
    const float var = q * (1.f / 512.f) - mu * mu;
    const float rstd = rsqrtf(var + LN_EPS);
    const float* g = G + (size_t)m * 512;
    const float* bt = Bt + (size_t)m * 512;
    float y0 = (x0 - mu) * rstd * g[tid] + bt[tid];
    float y1 = (x1 - mu) * rstd * g[tid + 256] + bt[tid + 256];
    if (RELU) { y0 = fmaxf(y0, 0.f); y1 = fmaxf(y1, 0.f); }
    yr[tid] = f2bf(y0);
    yr[tid + 256] = f2bf(y1);
}

// ---------------------------------------------------------------------------
// MFMA attention + fused mode-sum: one block per (b, h).
// ---------------------------------------------------------------------------
#define KP 72
#define VP 168
__global__ __launch_bounds__(256) void attn_mfma_kernel(
    const unsigned short* __restrict__ qkv, unsigned short* __restrict__ osum)
{
    const int b = blockIdx.x >> 3, h = blockIdx.x & 7;
    __shared__ __align__(16) unsigned short k_s[160 * KP];
    __shared__ __align__(16) unsigned short v_t[64 * VP];
    __shared__ __align__(16) unsigned short p_s[4][16 * VP];
    __shared__ float redsum[4][64];
    const int tid = threadIdx.x, lane = tid & 63, wid = tid >> 6;
    const int fr = lane & 15, ks = lane >> 4;
    const size_t base = (size_t)b * (150 * 1536) + h * 64;

    for (int idx = tid; idx < 160 * 8; idx += 256) {
        const int r = idx >> 3, c8 = (idx & 7) * 8;
        u16x8 v;
        if (r < 150) v = *(const u16x8*)(qkv + base + (size_t)r * 1536 + 512 + c8);
        else {
#pragma unroll
            for (int j = 0; j < 8; ++j) v[j] = 0;
        }
        *(u16x8*)(&k_s[r * KP + c8]) = v;
    }
    for (int idx = tid; idx < 160 * 8; idx += 256) {
        const int c8 = idx / 160, r = idx - c8 * 160;
        u16x8 v;
        if (r < 150) v = *(const u16x8*)(qkv + base + (size_t)r * 1536 + 1024 + c8 * 8);
        else {
#pragma unroll
            for (int j = 0; j < 8; ++j) v[j] = 0;
        }
#pragma unroll
        for (int j = 0; j < 8; ++j) v_t[(c8 * 8 + j) * VP + r] = v[j];
    }
    __syncthreads();

    unsigned short* pw = &p_s[wid][0];
    float psum[4] = {0.f, 0.f, 0.f, 0.f};

    for (int qt = wid; qt < 10; qt += 4) {
        const int qr = (qt * 16 + fr < 150) ? qt * 16 + fr : 149;
        const unsigned short* qp = qkv + base + (size_t)qr * 1536;
        s16x8 qa0 = *(const s16x8*)(qp + ks * 8);
        s16x8 qa1 = *(const s16x8*)(qp + 32 + ks * 8);

        f32x4 acc[10];
#pragma unroll
        for (int t = 0; t < 10; ++t)
#pragma unroll
            for (int r = 0; r < 4; ++r) acc[t][r] = 0.f;
#pragma unroll
        for (int t = 0; t < 10; ++t) {
            s16x8 kb0 = *(const s16x8*)(&k_s[(t * 16 + fr) * KP + ks * 8]);
            s16x8 kb1 = *(const s16x8*)(&k_s[(t * 16 + fr) * KP + 32 + ks * 8]);
            acc[t] = __builtin_amdgcn_mfma_f32_16x16x32_bf16(qa0, kb0, acc[t], 0, 0, 0);
            acc[t] = __builtin_amdgcn_mfma_f32_16x16x32_bf16(qa1, kb1, acc[t], 0, 0, 0);
        }

        const bool v9 = (fr < 6);
        float inv[4];
#pragma unroll
        for (int i = 0; i < 4; ++i) {
            float m = -1e30f;
#pragma unroll
            for (int t = 0; t < 9; ++t) m = fmaxf(m, acc[t][i]);
            if (v9) m = fmaxf(m, acc[9][i]);
#pragma unroll
            for (int off = 1; off < 16; off <<= 1) m = fmaxf(m, __shfl_xor(m, off));
            float s = 0.f;
#pragma unroll
            for (int t = 0; t < 10; ++t) {
                float e = 0.f;
                if (t < 9 || v9) e = __expf(0.125f * (acc[t][i] - m));
                s += e;
                pw[(ks * 4 + i) * VP + t * 16 + fr] = f2bf(e);
            }
#pragma unroll
            for (int off = 1; off < 16; off <<= 1) s += __shfl_xor(s, off);
            inv[i] = 1.f / s;
        }

        f32x4 o[4];
#pragma unroll
        for (int dt = 0; dt < 4; ++dt)
#pragma unroll
            for (int r = 0; r < 4; ++r) o[dt][r] = 0.f;
#pragma unroll
        for (int kc = 0; kc < 5; ++kc) {
            s16x8 pa = *(const s16x8*)(&pw[fr * VP + kc * 32 + ks * 8]);
#pragma unroll
            for (int dt = 0; dt < 4; ++dt) {
                s16x8 vb = *(const s16x8*)(&v_t[(dt * 16 + fr) * VP + kc * 32 + ks * 8]);
                o[dt] = __builtin_amdgcn_mfma_f32_16x16x32_bf16(pa, vb, o[dt], 0, 0, 0);
            }
        }

#pragma unroll
        for (int dt = 0; dt < 4; ++dt)
#pragma unroll
            for (int i = 0; i < 4; ++i) {
                const int q = qt * 16 + ks * 4 + i;
                if (q < 150) psum[dt] += o[dt][i] * inv[i];
            }
    }

#pragma unroll
    for (int dt = 0; dt < 4; ++dt) {
        float v = psum[dt];
        v += __shfl_xor(v, 16);
        v += __shfl_xor(v, 32);
        if (ks == 0) redsum[wid][dt * 16 + fr] = v;
    }
    __syncthreads();
    if (tid < 64) {
        const float s = redsum[0][tid] + redsum[1][tid] + redsum[2][tid] + redsum[3][tid];
        osum[(size_t)b * 512 + h * 64 + tid] = f2bf(s);
    }
}

// ---------------------------------------------------------------------------
extern "C" void kernel_launch(void* const* d_in, const int* in_sizes, int n_in,
                              void* d_out, int out_size, void* d_ws, size_t ws_size,
                              hipStream_t stream)
{
    (void)in_sizes; (void)n_in; (void)out_size; (void)ws_size;

    const int*   x          = (const int*)d_in[0];
    const float* emb        = (const float*)d_in[1];
    const float* W1         = (const float*)d_in[2];
    const float* b1         = (const float*)d_in[3];
    const float* ln1_g      = (const float*)d_in[4];
    const float* ln1_b      = (const float*)d_in[5];
    const float* W2         = (const float*)d_in[6];
    const float* b2         = (const float*)d_in[7];
    const float* dbias      = (const float*)d_in[8];
    const float* in_proj_w  = (const float*)d_in[9];
    const float* in_proj_b  = (const float*)d_in[10];
    const float* out_proj_w = (const float*)d_in[11];
    const float* out_proj_b = (const float*)d_in[12];
    const float* norm_g     = (const float*)d_in[13];
    const float* norm_b     = (const float*)d_in[14];
    const float* dec_w1     = (const float*)d_in[15];
    const float* dec_b1     = (const float*)d_in[16];
    const float* dec_w2     = (const float*)d_in[17];
    const float* dec_b2     = (const float*)d_in[18];

    char* ws = (char*)d_ws;
    unsigned short* e_bf  = (unsigned short*)(ws + 0x0);         // [256,512] bf16
    unsigned short* osum  = (unsigned short*)(ws + 0x40000);
    unsigned short* att1  = (unsigned short*)(ws + 0x80000);
    unsigned short* agg   = (unsigned short*)(ws + 0xC0000);
    unsigned short* dec1  = (unsigned short*)(ws + 0x100000);
    unsigned short* h1    = (unsigned short*)(ws + 0x200000);    // [B,M,D] 37.5MB
    unsigned short* mo    = (unsigned short*)(ws + 0x2800000);   // [B,M,D] 37.5MB
    unsigned short* qkvf  = (unsigned short*)(ws + 0x4E00000);   // [B,M,3D] 112.5MB
    unsigned short* Wbf1  = (unsigned short*)(ws + 0xBE80000);   // 78.6MB
    unsigned short* Wbf2  = (unsigned short*)(ws + 0x10980000);  // 78.6MB
    unsigned short* ipwbf = (unsigned short*)(ws + 0x15480000);  // 1.5MB
    unsigned short* opwbf = (unsigned short*)(ws + 0x15600000);  // 0.5MB
    unsigned short* dw1bf = (unsigned short*)(ws + 0x15700000);  // 0.25MB
    unsigned short* dw2bf = (unsigned short*)(ws + 0x15800000);  // 5MB

    // 1) prep: embed + cvt W1 + cvt small weights (one streaming launch)
    prep_kernel<<<PREP_BLOCKS, 256, 0, stream>>>(
        x, emb, e_bf, W1, Wbf1, in_proj_w, ipwbf, out_proj_w, opwbf,
        dec_w1, dw1bf, dec_w2, dw2bf);

    // 2) G1 (1200 gemm blocks) + fused cvt-W2 tail (2048 blocks)
    gemm_bf_kernel<512, false, false><<<1200 + 2048, 256, 0, stream>>>(
        e_bf, Wbf1, b1, nullptr, 1.f, h1,
        512, 4, 2, 1200,
        (size_t)0, 512, (size_t)512 * 512, 512, 512, 76800,
        W2, Wbf2, 150 * 512 * 512 / 8);

    // 3) LN(ln1_g, ln1_b) + ReLU, in-place on h1
    ln_kernel<true><<<38400, 256, 0, stream>>>(h1, ln1_g, ln1_b, h1, 150);

    // 4) G2: mo = h1 @ W2bf^T + b2 + dbias
    gemm_bf_kernel<512, false, false><<<1200, 256, 0, stream>>>(
        h1, Wbf2, b2, dbias, 1.f, mo,
        512, 4, 2, 1200,
        (size_t)512, 76800, (size_t)512 * 512, 512, 512, 76800,
        nullptr, nullptr, 0);

    // 5) qkv = mo @ in_proj^T + in_proj_b  (single launch, 3600 blocks)
    gemm_bf_kernel<512, false, false><<<3600, 256, 0, stream>>>(
        mo, ipwbf, in_proj_b, nullptr, 1.f, qkvf,
        1536, 12, 300, 3600,
        (size_t)0, 512, (size_t)0, 0, 0, 1536,
        nullptr, nullptr, 0);

    // 6) attention + fused mode-sum -> osum [256,512]
    attn_mfma_kernel<<<2048, 256, 0, stream>>>(qkvf, osum);

    // 7) attended_sum = osum @ out_proj^T + 150*out_proj_b
    gemm_bf_kernel<512, false, false><<<8, 256, 0, stream>>>(
        osum, opwbf, out_proj_b, nullptr, 150.f, att1,
        512, 4, 2, 8,
        (size_t)0, 512, (size_t)0, 0, 0, 512,
        nullptr, nullptr, 0);

    // 8) agg = LN(attended_sum; norm_g, norm_b)
    ln_kernel<false><<<256, 256, 0, stream>>>(att1, norm_g, norm_b, agg, 1);

    // 9) dec1 = ReLU(agg @ dec_w1^T + dec_b1)   [256,256]
    gemm_bf_kernel<512, true, false><<<4, 256, 0, stream>>>(
        agg, dw1bf, dec_b1, nullptr, 1.f, dec1,
        256, 2, 2, 4,
        (size_t)0, 512, (size_t)0, 0, 0, 256,
        nullptr, nullptr, 0);

    // 10) out = dec1 @ dec_w2^T + dec_b2   [256,10000] f32, K=256
    gemm_bf_kernel<256, false, true><<<158, 256, 0, stream>>>(
        dec1, dw2bf, dec_b2, nullptr, 1.f, d_out,
        10000, 79, 2, 158,
        (size_t)0, 256, (size_t)0, 0, 0, 10000,
        nullptr, nullptr, 0);
}

// Round 18
// 398.439 us; speedup vs baseline: 1.0243x; 1.0243x over previous
//
#include <hip/hip_runtime.h>

typedef __attribute__((ext_vector_type(8))) short s16x8;
typedef __attribute__((ext_vector_type(8))) unsigned short u16x8;
typedef __attribute__((ext_vector_type(4))) float f32x4;

#define LN_EPS 1e-5f

__device__ inline float bf2f(unsigned short u) {
    union { unsigned int i; float f; } x; x.i = ((unsigned int)u) << 16; return x.f;
}
__device__ inline unsigned short f2bf(float f) {
    unsigned int u = __builtin_bit_cast(unsigned int, f);
    u += 0x7FFFu + ((u >> 16) & 1u);
    return (unsigned short)(u >> 16);
}
__device__ inline unsigned int cvt_pk_bf16(float lo, float hi) {
    unsigned int r;
    asm("v_cvt_pk_bf16_f32 %0, %1, %2" : "=v"(r) : "v"(lo), "v"(hi));
    return r;
}
typedef __attribute__((address_space(1))) const unsigned int as1_u32;
typedef __attribute__((address_space(3))) unsigned int as3_u32;
__device__ inline void gl2lds16(const void* g, void* l) {
    __builtin_amdgcn_global_load_lds((as1_u32*)g, (as3_u32*)l, 16, 0, 0);
}

__device__ inline u16x8 cvt8(float4 a, float4 b) {
    union { unsigned int u[4]; u16x8 v; } r;
    r.u[0] = cvt_pk_bf16(a.x, a.y);
    r.u[1] = cvt_pk_bf16(a.z, a.w);
    r.u[2] = cvt_pk_bf16(b.x, b.y);
    r.u[3] = cvt_pk_bf16(b.z, b.w);
    return r.v;
}

// Burst-8 f32 -> bf16 stream (round-15 version; compiler-scheduled loads).
__device__ inline void cvt_stream(const float* __restrict__ src,
                                  unsigned short* __restrict__ dst,
                                  int n8, int lb, int nb, int tid)
{
    int i = lb * 256 + tid;
    const int stride = nb * 256;
    for (; i + 7 * stride < n8; i += 8 * stride) {
        float4 a[8], b[8];
#pragma unroll
        for (int j = 0; j < 8; ++j) {
            a[j] = ((const float4*)src)[2 * (i + j * stride)];
            b[j] = ((const float4*)src)[2 * (i + j * stride) + 1];
        }
#pragma unroll
        for (int j = 0; j < 8; ++j)
            ((u16x8*)dst)[i + j * stride] = cvt8(a[j], b[j]);
    }
    for (; i < n8; i += stride) {
        const float4 a = ((const float4*)src)[2 * i];
        const float4 b = ((const float4*)src)[2 * i + 1];
        ((u16x8*)dst)[i] = cvt8(a, b);
    }
}

// ---------------------------------------------------------------------------
// prep: embed STAGE-A (blocks 0..2047: 8 partial-blocks per batch row, each
// sums 16 gather rows -> f32 partials; serial depth 128 -> 16) + cvt W1 +
// small-weight cvts. Embed reduce happens in embed_reduce_kernel.
// ---------------------------------------------------------------------------
__global__ __launch_bounds__(256) void prep_kernel(
    const int* __restrict__ x, const float* __restrict__ emb,
    float* __restrict__ epart,
    const float* __restrict__ w1, unsigned short* __restrict__ w1b,
    const float* __restrict__ ipw, unsigned short* __restrict__ ipwb,
    const float* __restrict__ opw, unsigned short* __restrict__ opwb,
    const float* __restrict__ dw1, unsigned short* __restrict__ dw1b,
    const float* __restrict__ dw2, unsigned short* __restrict__ dw2b)
{
    const int tid = threadIdx.x;
    int b = blockIdx.x;
    if (b < 2048) {
        const int bb = b >> 3, j = b & 7;      // batch row, 16-row slice
        __shared__ int xs[16];
        if (tid < 16) xs[tid] = x[bb * 128 + j * 16 + tid];
        __syncthreads();
        float s0 = 0.f, s1 = 0.f;
#pragma unroll
        for (int i = 0; i < 16; ++i) {
            const float* r = emb + (size_t)xs[i] * 512;
            s0 += r[tid];
            s1 += r[tid + 256];
        }
        float* p = epart + (size_t)b * 512;
        p[tid] = s0;
        p[tid + 256] = s1;
        return;
    }
    b -= 2048;
    if (b < 2048) { cvt_stream(w1, w1b, 150 * 512 * 512 / 8, b, 2048, tid); return; }
    b -= 2048;
    if (b < 384) { cvt_stream(ipw, ipwb, 1536 * 512 / 8, b, 384, tid); return; }
    b -= 384;
    if (b < 128) { cvt_stream(opw, opwb, 512 * 512 / 8, b, 128, tid); return; }
    b -= 128;
    if (b < 64) { cvt_stream(dw1, dw1b, 256 * 512 / 8, b, 64, tid); return; }
    b -= 64;
    cvt_stream(dw2, dw2b, 10000 * 256 / 8, b, 1280, tid);
}
#define PREP_BLOCKS (2048 + 2048 + 384 + 128 + 64 + 1280)

// embed STAGE-B: e[b,d] = (1/128) * sum_j epart[b*8+j, d]
__global__ __launch_bounds__(512) void embed_reduce_kernel(
    const float* __restrict__ epart, unsigned short* __restrict__ e)
{
    const int b = blockIdx.x, tid = threadIdx.x;
    const float* p = epart + (size_t)b * 8 * 512 + tid;
    float s = 0.f;
#pragma unroll
    for (int j = 0; j < 8; ++j) s += p[j * 512];
    e[(size_t)b * 512 + tid] = f2bf(s * (1.f / 128.f));
}

// ---------------------------------------------------------------------------
// BK=32 2-phase all-bf16 GEMM (round-15 best config: 4 blocks/CU), optional
// fused conversion tail (blockIdx >= ngemm).
// ---------------------------------------------------------------------------
template<int K, bool RELU, bool F32OUT>
__global__ __launch_bounds__(256, 4) void gemm_bf_kernel(
    const unsigned short* __restrict__ A,
    const unsigned short* __restrict__ Wb,
    const float* __restrict__ bias1,
    const float* __restrict__ bias2,
    float bias_scale,
    void* __restrict__ Cv,
    int N, int gx, int gy, int ngemm,
    size_t strideA_mode, size_t lda,
    size_t strideW_mode, size_t strideB_mode,
    size_t strideC_mode, size_t ldc,
    const float* __restrict__ cvt_src, unsigned short* __restrict__ cvt_dst,
    int cvt_n8)
{
    constexpr int NSTEP = K / 32;
    const int tid = threadIdx.x;
    const int wgid = blockIdx.x;

    if (wgid >= ngemm) {
        cvt_stream(cvt_src, cvt_dst, cvt_n8, wgid - ngemm, gridDim.x - ngemm, tid);
        return;
    }

    const int q8 = ngemm >> 3, r8 = ngemm & 7;
    const int xcd = wgid & 7, sub = wgid >> 3;
    int p = (xcd < r8 ? xcd * (q8 + 1) : r8 * (q8 + 1) + (xcd - r8) * q8) + sub;
    const int bx = p % gx; p /= gx;
    const int by = p % gy;
    const int bz = p / gy;
    const int n0 = bx * 128, r0 = by * 128;

    __shared__ __align__(16) unsigned char lds[2][16384];  // [A 8K | B 8K]

    const int lane = tid & 63, wid = tid >> 6;
    const int fr = lane & 15, ks = lane >> 4;
    const int wr = (wid >> 1) * 64, wc = (wid & 1) * 64;

    const int Ia0 = (wid * 2 + 0) * 64 + lane;
    const int Ia1 = (wid * 2 + 1) * 64 + lane;
    const int ar0 = Ia0 >> 2, ac0 = (Ia0 & 3) ^ (ar0 & 3);
    const int ar1 = Ia1 >> 2, ac1 = (Ia1 & 3) ^ (ar1 & 3);
    const unsigned char* Aslab = (const unsigned char*)(A + (size_t)bz * strideA_mode);
    const unsigned char* aSrc0 = Aslab + (size_t)(r0 + ar0) * lda * 2 + ac0 * 16;
    const unsigned char* aSrc1 = Aslab + (size_t)(r0 + ar1) * lda * 2 + ac1 * 16;
    const unsigned char* Wslab = (const unsigned char*)(Wb + (size_t)bz * strideW_mode);
    const int br0 = min(n0 + ar0, N - 1), br1 = min(n0 + ar1, N - 1);
    const unsigned char* bSrc0 = Wslab + (size_t)br0 * K * 2 + ac0 * 16;
    const unsigned char* bSrc1 = Wslab + (size_t)br1 * K * 2 + ac1 * 16;

    f32x4 acc[4][4];
#pragma unroll
    for (int i = 0; i < 4; ++i)
#pragma unroll
        for (int j = 0; j < 4; ++j)
#pragma unroll
            for (int r = 0; r < 4; ++r) acc[i][j][r] = 0.f;

    auto stage = [&](int buf, int t) {
        gl2lds16(aSrc0 + (size_t)t * 64, &lds[buf][(wid * 2 + 0) * 1024]);
        gl2lds16(aSrc1 + (size_t)t * 64, &lds[buf][(wid * 2 + 1) * 1024]);
        gl2lds16(bSrc0 + (size_t)t * 64, &lds[buf][8192 + (wid * 2 + 0) * 1024]);
        gl2lds16(bSrc1 + (size_t)t * 64, &lds[buf][8192 + (wid * 2 + 1) * 1024]);
    };

    auto compute = [&](int buf) {
        const unsigned char* Ab = &lds[buf][0];
        const unsigned char* Bb = &lds[buf][8192];
        const int co = (ks ^ (fr & 3)) << 4;
        s16x8 af[4], bfr[4];
#pragma unroll
        for (int mi = 0; mi < 4; ++mi)
            af[mi] = *(const s16x8*)(Ab + (wr + mi * 16 + fr) * 64 + co);
#pragma unroll
        for (int ni = 0; ni < 4; ++ni)
            bfr[ni] = *(const s16x8*)(Bb + (wc + ni * 16 + fr) * 64 + co);
#pragma unroll
        for (int mi = 0; mi < 4; ++mi)
#pragma unroll
            for (int ni = 0; ni < 4; ++ni)
                acc[mi][ni] = __builtin_amdgcn_mfma_f32_16x16x32_bf16(af[mi], bfr[ni], acc[mi][ni], 0, 0, 0);
    };

    stage(0, 0);
    __syncthreads();

    for (int t = 0; t < NSTEP; t += 2) {
        stage(1, t + 1);
        compute(0);
        __syncthreads();
        if (t + 2 < NSTEP) stage(0, t + 2);
        compute(1);
        __syncthreads();
    }

    if (!F32OUT) {
        unsigned short* Cl = (unsigned short*)&lds[0][0];   // 128x128 bf16 = 32KB
#pragma unroll
        for (int ni = 0; ni < 4; ++ni) {
            const int col = n0 + wc + ni * 16 + fr;
            float bsum = 0.f;
            if (bias1) bsum += bias_scale * bias1[(size_t)bz * strideB_mode + col];
            if (bias2) bsum += bias2[(size_t)bz * strideB_mode + col];
#pragma unroll
            for (int mi = 0; mi < 4; ++mi)
#pragma unroll
                for (int r = 0; r < 4; ++r) {
                    float v = acc[mi][ni][r] + bsum;
                    if (RELU) v = fmaxf(v, 0.f);
                    Cl[(wr + mi * 16 + ks * 4 + r) * 128 + wc + ni * 16 + fr] = f2bf(v);
                }
        }
        __syncthreads();
        unsigned short* Cg = (unsigned short*)Cv + (size_t)bz * strideC_mode;
#pragma unroll
        for (int it = 0; it < 8; ++it) {
            const int c = it * 256 + tid;
            const int row = c >> 4, ch = c & 15;
            u16x8 v = *(const u16x8*)(&Cl[row * 128 + ch * 8]);
            *(u16x8*)(Cg + (size_t)(r0 + row) * ldc + n0 + ch * 8) = v;
        }
    } else {
#pragma unroll
        for (int ni = 0; ni < 4; ++ni) {
            const int col = n0 + wc + ni * 16 + fr;
            if (col < N) {
                float bsum = 0.f;
                if (bias1) bsum += bias_scale * bias1[(size_t)bz * strideB_mode + col];
                if (bias2) bsum += bias2[(size_t)bz * strideB_mode + col];
#pragma unroll
                for (int mi = 0; mi < 4; ++mi)
#pragma unroll
                    for (int r = 0; r < 4; ++r) {
                        const int row = r0 + wr + mi * 16 + ks * 4 + r;
                        float v = acc[mi][ni][r] + bsum;
                        if (RELU) v = fmaxf(v, 0.f);
                        ((float*)Cv)[(size_t)bz * strideC_mode + (size_t)row * ldc + col] = v;
                    }
            }
        }
    }
}

// ---------------------------------------------------------------------------
// Row LayerNorm over D=512 (+opt ReLU), gamma/beta f32, m = row % M.
// ---------------------------------------------------------------------------
template<bool RELU>
__global__ __launch_bounds__(256) void ln_kernel(
    const unsigned short* __restrict__ X,
    const float* __restrict__ G,
    const float* __restrict__ Bt,
    unsigned short* __restrict__ Y,
    int M)
{
    const int row = blockIdx.x;
    const int m = row % M;
    const unsigned short* xr = X + (size_t)row * 512;
    unsigned short* yr = Y + (size_t)row * 512;
    const int tid = threadIdx.x;
    const float x0 = bf2f(xr[tid]), x1 = bf2f(xr[tid + 256]);
    float s = x0 + x1, q = x0 * x0 + x1 * x1;
#pragma unroll
    for (int off = 32; off; off >>= 1) {
        s += __shfl_xor(s, off);
        q += __shfl_xor(q, off);
    }
    __shared__ float red[4][2];
    const int wid = tid >> 6, lane = tid & 63;
    if (lane == 0) { red[wid][0] = s; red[wid][1] = q; }
    __syncthreads();
    s = red[0][0] + red[1][0] + red[2][0] + red[3][0];
    q = red[0][1] + red[1][1] + red[2][1] + red[3][1];
    const float mu = s * (1.f / 512.f);
    const float var = q * (1.f / 512.f) - mu * mu;
    const float rstd = rsqrtf(var + LN_EPS);
    const float* g = G + (size_t)m * 512;
    const float* bt = Bt + (size_t)m * 512;
    float y0 = (x0 - mu) * rstd * g[tid] + bt[tid];
    float y1 = (x1 - mu) * rstd * g[tid + 256] + bt[tid + 256];
    if (RELU) { y0 = fmaxf(y0, 0.f); y1 = fmaxf(y1, 0.f); }
    yr[tid] = f2bf(y0);
    yr[tid + 256] = f2bf(y1);
}

// ---------------------------------------------------------------------------
// MFMA attention + fused mode-sum: one block per (b, h).
// ---------------------------------------------------------------------------
#define KP 72
#define VP 168
__global__ __launch_bounds__(256) void attn_mfma_kernel(
    const unsigned short* __restrict__ qkv, unsigned short* __restrict__ osum)
{
    const int b = blockIdx.x >> 3, h = blockIdx.x & 7;
    __shared__ __align__(16) unsigned short k_s[160 * KP];
    __shared__ __align__(16) unsigned short v_t[64 * VP];
    __shared__ __align__(16) unsigned short p_s[4][16 * VP];
    __shared__ float redsum[4][64];
    const int tid = threadIdx.x, lane = tid & 63, wid = tid >> 6;
    const int fr = lane & 15, ks = lane >> 4;
    const size_t base = (size_t)b * (150 * 1536) + h * 64;

    for (int idx = tid; idx < 160 * 8; idx += 256) {
        const int r = idx >> 3, c8 = (idx & 7) * 8;
        u16x8 v;
        if (r < 150) v = *(const u16x8*)(qkv + base + (size_t)r * 1536 + 512 + c8);
        else {
#pragma unroll
            for (int j = 0; j < 8; ++j) v[j] = 0;
        }
        *(u16x8*)(&k_s[r * KP + c8]) = v;
    }
    for (int idx = tid; idx < 160 * 8; idx += 256) {
        const int c8 = idx / 160, r = idx - c8 * 160;
        u16x8 v;
        if (r < 150) v = *(const u16x8*)(qkv + base + (size_t)r * 1536 + 1024 + c8 * 8);
        else {
#pragma unroll
            for (int j = 0; j < 8; ++j) v[j] = 0;
        }
#pragma unroll
        for (int j = 0; j < 8; ++j) v_t[(c8 * 8 + j) * VP + r] = v[j];
    }
    __syncthreads();

    unsigned short* pw = &p_s[wid][0];
    float psum[4] = {0.f, 0.f, 0.f, 0.f};

    for (int qt = wid; qt < 10; qt += 4) {
        const int qr = (qt * 16 + fr < 150) ? qt * 16 + fr : 149;
        const unsigned short* qp = qkv + base + (size_t)qr * 1536;
        s16x8 qa0 = *(const s16x8*)(qp + ks * 8);
        s16x8 qa1 = *(const s16x8*)(qp + 32 + ks * 8);

        f32x4 acc[10];
#pragma unroll
        for (int t = 0; t < 10; ++t)
#pragma unroll
            for (int r = 0; r < 4; ++r) acc[t][r] = 0.f;
#pragma unroll
        for (int t = 0; t < 10; ++t) {
            s16x8 kb0 = *(const s16x8*)(&k_s[(t * 16 + fr) * KP + ks * 8]);
            s16x8 kb1 = *(const s16x8*)(&k_s[(t * 16 + fr) * KP + 32 + ks * 8]);
            acc[t] = __builtin_amdgcn_mfma_f32_16x16x32_bf16(qa0, kb0, acc[t], 0, 0, 0);
            acc[t] = __builtin_amdgcn_mfma_f32_16x16x32_bf16(qa1, kb1, acc[t], 0, 0, 0);
        }

        const bool v9 = (fr < 6);
        float inv[4];
#pragma unroll
        for (int i = 0; i < 4; ++i) {
            float m = -1e30f;
#pragma unroll
            for (int t = 0; t < 9; ++t) m = fmaxf(m, acc[t][i]);
            if (v9) m = fmaxf(m, acc[9][i]);
#pragma unroll
            for (int off = 1; off < 16; off <<= 1) m = fmaxf(m, __shfl_xor(m, off));
            float s = 0.f;
#pragma unroll
            for (int t = 0; t < 10; ++t) {
                float e = 0.f;
                if (t < 9 || v9) e = __expf(0.125f * (acc[t][i] - m));
                s += e;
                pw[(ks * 4 + i) * VP + t * 16 + fr] = f2bf(e);
            }
#pragma unroll
            for (int off = 1; off < 16; off <<= 1) s += __shfl_xor(s, off);
            inv[i] = 1.f / s;
        }

        f32x4 o[4];
#pragma unroll
        for (int dt = 0; dt < 4; ++dt)
#pragma unroll
            for (int r = 0; r < 4; ++r) o[dt][r] = 0.f;
#pragma unroll
        for (int kc = 0; kc < 5; ++kc) {
            s16x8 pa = *(const s16x8*)(&pw[fr * VP + kc * 32 + ks * 8]);
#pragma unroll
            for (int dt = 0; dt < 4; ++dt) {
                s16x8 vb = *(const s16x8*)(&v_t[(dt * 16 + fr) * VP + kc * 32 + ks * 8]);
                o[dt] = __builtin_amdgcn_mfma_f32_16x16x32_bf16(pa, vb, o[dt], 0, 0, 0);
            }
        }

#pragma unroll
        for (int dt = 0; dt < 4; ++dt)
#pragma unroll
            for (int i = 0; i < 4; ++i) {
                const int q = qt * 16 + ks * 4 + i;
                if (q < 150) psum[dt] += o[dt][i] * inv[i];
            }
    }

#pragma unroll
    for (int dt = 0; dt < 4; ++dt) {
        float v = psum[dt];
        v += __shfl_xor(v, 16);
        v += __shfl_xor(v, 32);
        if (ks == 0) redsum[wid][dt * 16 + fr] = v;
    }
    __syncthreads();
    if (tid < 64) {
        const float s = redsum[0][tid] + redsum[1][tid] + redsum[2][tid] + redsum[3][tid];
        osum[(size_t)b * 512 + h * 64 + tid] = f2bf(s);
    }
}

// ---------------------------------------------------------------------------
extern "C" void kernel_launch(void* const* d_in, const int* in_sizes, int n_in,
                              void* d_out, int out_size, void* d_ws, size_t ws_size,
                              hipStream_t stream)
{
    (void)in_sizes; (void)n_in; (void)out_size; (void)ws_size;

    const int*   x          = (const int*)d_in[0];
    const float* emb        = (const float*)d_in[1];
    const float* W1         = (const float*)d_in[2];
    const float* b1         = (const float*)d_in[3];
    const float* ln1_g      = (const float*)d_in[4];
    const float* ln1_b      = (const float*)d_in[5];
    const float* W2         = (const float*)d_in[6];
    const float* b2         = (const float*)d_in[7];
    const float* dbias      = (const float*)d_in[8];
    const float* in_proj_w  = (const float*)d_in[9];
    const float* in_proj_b  = (const float*)d_in[10];
    const float* out_proj_w = (const float*)d_in[11];
    const float* out_proj_b = (const float*)d_in[12];
    const float* norm_g     = (const float*)d_in[13];
    const float* norm_b     = (const float*)d_in[14];
    const float* dec_w1     = (const float*)d_in[15];
    const float* dec_b1     = (const float*)d_in[16];
    const float* dec_w2     = (const float*)d_in[17];
    const float* dec_b2     = (const float*)d_in[18];

    char* ws = (char*)d_ws;
    unsigned short* e_bf  = (unsigned short*)(ws + 0x0);         // [256,512] bf16
    unsigned short* osum  = (unsigned short*)(ws + 0x40000);
    unsigned short* att1  = (unsigned short*)(ws + 0x80000);
    unsigned short* agg   = (unsigned short*)(ws + 0xC0000);
    unsigned short* dec1  = (unsigned short*)(ws + 0x100000);
    unsigned short* h1    = (unsigned short*)(ws + 0x200000);    // [B,M,D] 37.5MB
    unsigned short* mo    = (unsigned short*)(ws + 0x2800000);   // [B,M,D] 37.5MB
    unsigned short* qkvf  = (unsigned short*)(ws + 0x4E00000);   // [B,M,3D] 112.5MB
    unsigned short* Wbf1  = (unsigned short*)(ws + 0xBE80000);   // 78.6MB
    unsigned short* Wbf2  = (unsigned short*)(ws + 0x10980000);  // 78.6MB
    unsigned short* ipwbf = (unsigned short*)(ws + 0x15480000);  // 1.5MB
    unsigned short* opwbf = (unsigned short*)(ws + 0x15600000);  // 0.5MB
    unsigned short* dw1bf = (unsigned short*)(ws + 0x15700000);  // 0.25MB
    unsigned short* dw2bf = (unsigned short*)(ws + 0x15800000);  // 5MB
    float*          epart = (float*)(ws + 0x15D00000);           // [2048,512] f32 4MB

    // 1) prep: embed stage-A + cvt W1 + cvt small weights (one launch)
    prep_kernel<<<PREP_BLOCKS, 256, 0, stream>>>(
        x, emb, epart, W1, Wbf1, in_proj_w, ipwbf, out_proj_w, opwbf,
        dec_w1, dw1bf, dec_w2, dw2bf);

    // 1b) embed stage-B reduce -> e_bf
    embed_reduce_kernel<<<256, 512, 0, stream>>>(epart, e_bf);

    // 2) G1 (1200 gemm blocks) + fused cvt-W2 tail (2048 blocks)
    gemm_bf_kernel<512, false, false><<<1200 + 2048, 256, 0, stream>>>(
        e_bf, Wbf1, b1, nullptr, 1.f, h1,
        512, 4, 2, 1200,
        (size_t)0, 512, (size_t)512 * 512, 512, 512, 76800,
        W2, Wbf2, 150 * 512 * 512 / 8);

    // 3) LN(ln1_g, ln1_b) + ReLU, in-place on h1
    ln_kernel<true><<<38400, 256, 0, stream>>>(h1, ln1_g, ln1_b, h1, 150);

    // 4) G2: mo = h1 @ W2bf^T + b2 + dbias
    gemm_bf_kernel<512, false, false><<<1200, 256, 0, stream>>>(
        h1, Wbf2, b2, dbias, 1.f, mo,
        512, 4, 2, 1200,
        (size_t)512, 76800, (size_t)512 * 512, 512, 512, 76800,
        nullptr, nullptr, 0);

    // 5) qkv = mo @ in_proj^T + in_proj_b  (single launch, 3600 blocks)
    gemm_bf_kernel<512, false, false><<<3600, 256, 0, stream>>>(
        mo, ipwbf, in_proj_b, nullptr, 1.f, qkvf,
        1536, 12, 300, 3600,
        (size_t)0, 512, (size_t)0, 0, 0, 1536,
        nullptr, nullptr, 0);

    // 6) attention + fused mode-sum -> osum [256,512]
    attn_mfma_kernel<<<2048, 256, 0, stream>>>(qkvf, osum);

    // 7) attended_sum = osum @ out_proj^T + 150*out_proj_b
    gemm_bf_kernel<512, false, false><<<8, 256, 0, stream>>>(
        osum, opwbf, out_proj_b, nullptr, 150.f, att1,
        512, 4, 2, 8,
        (size_t)0, 512, (size_t)0, 0, 0, 512,
        nullptr, nullptr, 0);

    // 8) agg = LN(attended_sum; norm_g, norm_b)
    ln_kernel<false><<<256, 256, 0, stream>>>(att1, norm_g, norm_b, agg, 1);

    // 9) dec1 = ReLU(agg @ dec_w1^T + dec_b1)   [256,256]
    gemm_bf_kernel<512, true, false><<<4, 256, 0, stream>>>(
        agg, dw1bf, dec_b1, nullptr, 1.f, dec1,
        256, 2, 2, 4,
        (size_t)0, 512, (size_t)0, 0, 0, 256,
        nullptr, nullptr, 0);

    // 10) out = dec1 @ dec_w2^T + dec_b2   [256,10000] f32, K=256
    gemm_bf_kernel<256, false, true><<<158, 256, 0, stream>>>(
        dec1, dw2bf, dec_b2, nullptr, 1.f, d_out,
        10000, 79, 2, 158,
        (size_t)0, 256, (size_t)0, 0, 0, 10000,
        nullptr, nullptr, 0);
}

// Round 20
// 392.742 us; speedup vs baseline: 1.0391x; 1.0145x over previous
//
#include <hip/hip_runtime.h>

typedef __attribute__((ext_vector_type(8))) short s16x8;
typedef __attribute__((ext_vector_type(8))) unsigned short u16x8;
typedef __attribute__((ext_vector_type(4))) float f32x4;

#define LN_EPS 1e-5f

__device__ inline float bf2f(unsigned short u) {
    union { unsigned int i; float f; } x; x.i = ((unsigned int)u) << 16; return x.f;
}
__device__ inline unsigned short f2bf(float f) {
    unsigned int u = __builtin_bit_cast(unsigned int, f);
    u += 0x7FFFu + ((u >> 16) & 1u);
    return (unsigned short)(u >> 16);
}
__device__ inline unsigned int cvt_pk_bf16(float lo, float hi) {
    unsigned int r;
    asm("v_cvt_pk_bf16_f32 %0, %1, %2" : "=v"(r) : "v"(lo), "v"(hi));
    return r;
}
typedef __attribute__((address_space(1))) const unsigned int as1_u32;
typedef __attribute__((address_space(3))) unsigned int as3_u32;
__device__ inline void gl2lds16(const void* g, void* l) {
    __builtin_amdgcn_global_load_lds((as1_u32*)g, (as3_u32*)l, 16, 0, 0);
}

__device__ inline u16x8 cvt8v(f32x4 a, f32x4 b) {
    union { unsigned int u[4]; u16x8 v; } r;
    r.u[0] = cvt_pk_bf16(a.x, a.y);
    r.u[1] = cvt_pk_bf16(a.z, a.w);
    r.u[2] = cvt_pk_bf16(b.x, b.y);
    r.u[3] = cvt_pk_bf16(b.z, b.w);
    return r.v;
}
__device__ inline u16x8 cvt8(float4 a, float4 b) {
    union { unsigned int u[4]; u16x8 v; } r;
    r.u[0] = cvt_pk_bf16(a.x, a.y);
    r.u[1] = cvt_pk_bf16(a.z, a.w);
    r.u[2] = cvt_pk_bf16(b.x, b.y);
    r.u[3] = cvt_pk_bf16(b.z, b.w);
    return r.v;
}

// Burst-8 f32 -> bf16 stream with NON-TEMPORAL loads/stores (nt bit via
// ext_vector types — HIP float4 struct is rejected by the builtin). The
// stream is read-once/write-once; bypassing cache fill-allocate avoids
// thrashing L2/L3 with 350 MB of dead lines (theory: the ~2.2 TB/s wall).
__device__ inline void cvt_stream(const float* __restrict__ src,
                                  unsigned short* __restrict__ dst,
                                  int n8, int lb, int nb, int tid)
{
    const f32x4* __restrict__ s4 = (const f32x4*)src;
    u16x8* __restrict__ d8 = (u16x8*)dst;
    int i = lb * 256 + tid;
    const int stride = nb * 256;
    for (; i + 7 * stride < n8; i += 8 * stride) {
        f32x4 a[8], b[8];
#pragma unroll
        for (int j = 0; j < 8; ++j) {
            a[j] = __builtin_nontemporal_load(&s4[2 * (i + j * stride)]);
            b[j] = __builtin_nontemporal_load(&s4[2 * (i + j * stride) + 1]);
        }
#pragma unroll
        for (int j = 0; j < 8; ++j) {
            u16x8 v = cvt8v(a[j], b[j]);
            __builtin_nontemporal_store(v, &d8[i + j * stride]);
        }
    }
    for (; i < n8; i += stride) {
        const f32x4 a = __builtin_nontemporal_load(&s4[2 * i]);
        const f32x4 b = __builtin_nontemporal_load(&s4[2 * i + 1]);
        u16x8 v = cvt8v(a, b);
        __builtin_nontemporal_store(v, &d8[i]);
    }
}

// ---------------------------------------------------------------------------
// prep: embed STAGE-A (blocks 0..2047) + cvt W1 + small-weight cvts.
// ---------------------------------------------------------------------------
__global__ __launch_bounds__(256) void prep_kernel(
    const int* __restrict__ x, const float* __restrict__ emb,
    float* __restrict__ epart,
    const float* __restrict__ w1, unsigned short* __restrict__ w1b,
    const float* __restrict__ ipw, unsigned short* __restrict__ ipwb,
    const float* __restrict__ opw, unsigned short* __restrict__ opwb,
    const float* __restrict__ dw1, unsigned short* __restrict__ dw1b,
    const float* __restrict__ dw2, unsigned short* __restrict__ dw2b)
{
    const int tid = threadIdx.x;
    int b = blockIdx.x;
    if (b < 2048) {
        const int bb = b >> 3, j = b & 7;      // batch row, 16-row slice
        __shared__ int xs[16];
        if (tid < 16) xs[tid] = x[bb * 128 + j * 16 + tid];
        __syncthreads();
        float s0 = 0.f, s1 = 0.f;
#pragma unroll
        for (int i = 0; i < 16; ++i) {
            const float* r = emb + (size_t)xs[i] * 512;
            s0 += r[tid];
            s1 += r[tid + 256];
        }
        float* p = epart + (size_t)b * 512;
        p[tid] = s0;
        p[tid + 256] = s1;
        return;
    }
    b -= 2048;
    if (b < 2048) { cvt_stream(w1, w1b, 150 * 512 * 512 / 8, b, 2048, tid); return; }
    b -= 2048;
    if (b < 384) { cvt_stream(ipw, ipwb, 1536 * 512 / 8, b, 384, tid); return; }
    b -= 384;
    if (b < 128) { cvt_stream(opw, opwb, 512 * 512 / 8, b, 128, tid); return; }
    b -= 128;
    if (b < 64) { cvt_stream(dw1, dw1b, 256 * 512 / 8, b, 64, tid); return; }
    b -= 64;
    cvt_stream(dw2, dw2b, 10000 * 256 / 8, b, 1280, tid);
}
#define PREP_BLOCKS (2048 + 2048 + 384 + 128 + 64 + 1280)

// embed STAGE-B: e[b,d] = (1/128) * sum_j epart[b*8+j, d]
__global__ __launch_bounds__(512) void embed_reduce_kernel(
    const float* __restrict__ epart, unsigned short* __restrict__ e)
{
    const int b = blockIdx.x, tid = threadIdx.x;
    const float* p = epart + (size_t)b * 8 * 512 + tid;
    float s = 0.f;
#pragma unroll
    for (int j = 0; j < 8; ++j) s += p[j * 512];
    e[(size_t)b * 512 + tid] = f2bf(s * (1.f / 128.f));
}

// ---------------------------------------------------------------------------
// BK=32 2-phase all-bf16 GEMM (4 blocks/CU), optional fused conversion tail.
// ---------------------------------------------------------------------------
template<int K, bool RELU, bool F32OUT>
__global__ __launch_bounds__(256, 4) void gemm_bf_kernel(
    const unsigned short* __restrict__ A,
    const unsigned short* __restrict__ Wb,
    const float* __restrict__ bias1,
    const float* __restrict__ bias2,
    float bias_scale,
    void* __restrict__ Cv,
    int N, int gx, int gy, int ngemm,
    size_t strideA_mode, size_t lda,
    size_t strideW_mode, size_t strideB_mode,
    size_t strideC_mode, size_t ldc,
    const float* __restrict__ cvt_src, unsigned short* __restrict__ cvt_dst,
    int cvt_n8)
{
    constexpr int NSTEP = K / 32;
    const int tid = threadIdx.x;
    const int wgid = blockIdx.x;

    if (wgid >= ngemm) {
        cvt_stream(cvt_src, cvt_dst, cvt_n8, wgid - ngemm, gridDim.x - ngemm, tid);
        return;
    }

    const int q8 = ngemm >> 3, r8 = ngemm & 7;
    const int xcd = wgid & 7, sub = wgid >> 3;
    int p = (xcd < r8 ? xcd * (q8 + 1) : r8 * (q8 + 1) + (xcd - r8) * q8) + sub;
    const int bx = p % gx; p /= gx;
    const int by = p % gy;
    const int bz = p / gy;
    const int n0 = bx * 128, r0 = by * 128;

    __shared__ __align__(16) unsigned char lds[2][16384];  // [A 8K | B 8K]

    const int lane = tid & 63, wid = tid >> 6;
    const int fr = lane & 15, ks = lane >> 4;
    const int wr = (wid >> 1) * 64, wc = (wid & 1) * 64;

    const int Ia0 = (wid * 2 + 0) * 64 + lane;
    const int Ia1 = (wid * 2 + 1) * 64 + lane;
    const int ar0 = Ia0 >> 2, ac0 = (Ia0 & 3) ^ (ar0 & 3);
    const int ar1 = Ia1 >> 2, ac1 = (Ia1 & 3) ^ (ar1 & 3);
    const unsigned char* Aslab = (const unsigned char*)(A + (size_t)bz * strideA_mode);
    const unsigned char* aSrc0 = Aslab + (size_t)(r0 + ar0) * lda * 2 + ac0 * 16;
    const unsigned char* aSrc1 = Aslab + (size_t)(r0 + ar1) * lda * 2 + ac1 * 16;
    const unsigned char* Wslab = (const unsigned char*)(Wb + (size_t)bz * strideW_mode);
    const int br0 = min(n0 + ar0, N - 1), br1 = min(n0 + ar1, N - 1);
    const unsigned char* bSrc0 = Wslab + (size_t)br0 * K * 2 + ac0 * 16;
    const unsigned char* bSrc1 = Wslab + (size_t)br1 * K * 2 + ac1 * 16;

    f32x4 acc[4][4];
#pragma unroll
    for (int i = 0; i < 4; ++i)
#pragma unroll
        for (int j = 0; j < 4; ++j)
#pragma unroll
            for (int r = 0; r < 4; ++r) acc[i][j][r] = 0.f;

    auto stage = [&](int buf, int t) {
        gl2lds16(aSrc0 + (size_t)t * 64, &lds[buf][(wid * 2 + 0) * 1024]);
        gl2lds16(aSrc1 + (size_t)t * 64, &lds[buf][(wid * 2 + 1) * 1024]);
        gl2lds16(bSrc0 + (size_t)t * 64, &lds[buf][8192 + (wid * 2 + 0) * 1024]);
        gl2lds16(bSrc1 + (size_t)t * 64, &lds[buf][8192 + (wid * 2 + 1) * 1024]);
    };

    auto compute = [&](int buf) {
        const unsigned char* Ab = &lds[buf][0];
        const unsigned char* Bb = &lds[buf][8192];
        const int co = (ks ^ (fr & 3)) << 4;
        s16x8 af[4], bfr[4];
#pragma unroll
        for (int mi = 0; mi < 4; ++mi)
            af[mi] = *(const s16x8*)(Ab + (wr + mi * 16 + fr) * 64 + co);
#pragma unroll
        for (int ni = 0; ni < 4; ++ni)
            bfr[ni] = *(const s16x8*)(Bb + (wc + ni * 16 + fr) * 64 + co);
#pragma unroll
        for (int mi = 0; mi < 4; ++mi)
#pragma unroll
            for (int ni = 0; ni < 4; ++ni)
                acc[mi][ni] = __builtin_amdgcn_mfma_f32_16x16x32_bf16(af[mi], bfr[ni], acc[mi][ni], 0, 0, 0);
    };

    stage(0, 0);
    __syncthreads();

    for (int t = 0; t < NSTEP; t += 2) {
        stage(1, t + 1);
        compute(0);
        __syncthreads();
        if (t + 2 < NSTEP) stage(0, t + 2);
        compute(1);
        __syncthreads();
    }

    if (!F32OUT) {
        unsigned short* Cl = (unsigned short*)&lds[0][0];   // 128x128 bf16 = 32KB
#pragma unroll
        for (int ni = 0; ni < 4; ++ni) {
            const int col = n0 + wc + ni * 16 + fr;
            float bsum = 0.f;
            if (bias1) bsum += bias_scale * bias1[(size_t)bz * strideB_mode + col];
            if (bias2) bsum += bias2[(size_t)bz * strideB_mode + col];
#pragma unroll
            for (int mi = 0; mi < 4; ++mi)
#pragma unroll
                for (int r = 0; r < 4; ++r) {
                    float v = acc[mi][ni][r] + bsum;
                    if (RELU) v = fmaxf(v, 0.f);
                    Cl[(wr + mi * 16 + ks * 4 + r) * 128 + wc + ni * 16 + fr] = f2bf(v);
                }
        }
        __syncthreads();
        unsigned short* Cg = (unsigned short*)Cv + (size_t)bz * strideC_mode;
#pragma unroll
        for (int it = 0; it < 8; ++it) {
            const int c = it * 256 + tid;
            const int row = c >> 4, ch = c & 15;
            u16x8 v = *(const u16x8*)(&Cl[row * 128 + ch * 8]);
            *(u16x8*)(Cg + (size_t)(r0 + row) * ldc + n0 + ch * 8) = v;
        }
    } else {
#pragma unroll
        for (int ni = 0; ni < 4; ++ni) {
            const int col = n0 + wc + ni * 16 + fr;
            if (col < N) {
                float bsum = 0.f;
                if (bias1) bsum += bias_scale * bias1[(size_t)bz * strideB_mode + col];
                if (bias2) bsum += bias2[(size_t)bz * strideB_mode + col];
#pragma unroll
                for (int mi = 0; mi < 4; ++mi)
#pragma unroll
                    for (int r = 0; r < 4; ++r) {
                        const int row = r0 + wr + mi * 16 + ks * 4 + r;
                        float v = acc[mi][ni][r] + bsum;
                        if (RELU) v = fmaxf(v, 0.f);
                        ((float*)Cv)[(size_t)bz * strideC_mode + (size_t)row * ldc + col] = v;
                    }
            }
        }
    }
}

// ---------------------------------------------------------------------------
// Row LayerNorm over D=512 (+opt ReLU), gamma/beta f32, m = row % M.
// ---------------------------------------------------------------------------
template<bool RELU>
__global__ __launch_bounds__(256) void ln_kernel(
    const unsigned short* __restrict__ X,
    const float* __restrict__ G,
    const float* __restrict__ Bt,
    unsigned short* __restrict__ Y,
    int M)
{
    const int row = blockIdx.x;
    const int m = row % M;
    const unsigned short* xr = X + (size_t)row * 512;
    unsigned short* yr = Y + (size_t)row * 512;
    const int tid = threadIdx.x;
    const float x0 = bf2f(xr[tid]), x1 = bf2f(xr[tid + 256]);
    float s = x0 + x1, q = x0 * x0 + x1 * x1;
#pragma unroll
    for (int off = 32; off; off >>= 1) {
        s += __shfl_xor(s, off);
        q += __shfl_xor(q, off);
    }
    __shared__ float red[4][2];
    const int wid = tid >> 6, lane = tid & 63;
    if (lane == 0) { red[wid][0] = s; red[wid][1] = q; }
    __syncthreads();
    s = red[0][0] + red[1][0] + red[2][0] + red[3][0];
    q = red[0][1] + red[1][1] + red[2][1] + red[3][1];
    const float mu = s * (1.f / 512.f);
    const float var = q * (1.f / 512.f) - mu * mu;
    const float rstd = rsqrtf(var + LN_EPS);
    const float* g = G + (size_t)m * 512;
    const float* bt = Bt + (size_t)m * 512;
    float y0 = (x0 - mu) * rstd * g[tid] + bt[tid];
    float y1 = (x1 - mu) * rstd * g[tid + 256] + bt[tid + 256];
    if (RELU) { y0 = fmaxf(y0, 0.f); y1 = fmaxf(y1, 0.f); }
    yr[tid] = f2bf(y0);
    yr[tid + 256] = f2bf(y1);
}

// ---------------------------------------------------------------------------
// MFMA attention + fused mode-sum: one block per (b, h).
// ---------------------------------------------------------------------------
#define KP 72
#define VP 168
__global__ __launch_bounds__(256) void attn_mfma_kernel(
    const unsigned short* __restrict__ qkv, unsigned short* __restrict__ osum)
{
    const int b = blockIdx.x >> 3, h = blockIdx.x & 7;
    __shared__ __align__(16) unsigned short k_s[160 * KP];
    __shared__ __align__(16) unsigned short v_t[64 * VP];
    __shared__ __align__(16) unsigned short p_s[4][16 * VP];
    __shared__ float redsum[4][64];
    const int tid = threadIdx.x, lane = tid & 63, wid = tid >> 6;
    const int fr = lane & 15, ks = lane >> 4;
    const size_t base = (size_t)b * (150 * 1536) + h * 64;

    for (int idx = tid; idx < 160 * 8; idx += 256) {
        const int r = idx >> 3, c8 = (idx & 7) * 8;
        u16x8 v;
        if (r < 150) v = *(const u16x8*)(qkv + base + (size_t)r * 1536 + 512 + c8);
        else {
#pragma unroll
            for (int j = 0; j < 8; ++j) v[j] = 0;
        }
        *(u16x8*)(&k_s[r * KP + c8]) = v;
    }
    for (int idx = tid; idx < 160 * 8; idx += 256) {
        const int c8 = idx / 160, r = idx - c8 * 160;
        u16x8 v;
        if (r < 150) v = *(const u16x8*)(qkv + base + (size_t)r * 1536 + 1024 + c8 * 8);
        else {
#pragma unroll
            for (int j = 0; j < 8; ++j) v[j] = 0;
        }
#pragma unroll
        for (int j = 0; j < 8; ++j) v_t[(c8 * 8 + j) * VP + r] = v[j];
    }
    __syncthreads();

    unsigned short* pw = &p_s[wid][0];
    float psum[4] = {0.f, 0.f, 0.f, 0.f};

    for (int qt = wid; qt < 10; qt += 4) {
        const int qr = (qt * 16 + fr < 150) ? qt * 16 + fr : 149;
        const unsigned short* qp = qkv + base + (size_t)qr * 1536;
        s16x8 qa0 = *(const s16x8*)(qp + ks * 8);
        s16x8 qa1 = *(const s16x8*)(qp + 32 + ks * 8);

        f32x4 acc[10];
#pragma unroll
        for (int t = 0; t < 10; ++t)
#pragma unroll
            for (int r = 0; r < 4; ++r) acc[t][r] = 0.f;
#pragma unroll
        for (int t = 0; t < 10; ++t) {
            s16x8 kb0 = *(const s16x8*)(&k_s[(t * 16 + fr) * KP + ks * 8]);
            s16x8 kb1 = *(const s16x8*)(&k_s[(t * 16 + fr) * KP + 32 + ks * 8]);
            acc[t] = __builtin_amdgcn_mfma_f32_16x16x32_bf16(qa0, kb0, acc[t], 0, 0, 0);
            acc[t] = __builtin_amdgcn_mfma_f32_16x16x32_bf16(qa1, kb1, acc[t], 0, 0, 0);
        }

        const bool v9 = (fr < 6);
        float inv[4];
#pragma unroll
        for (int i = 0; i < 4; ++i) {
            float m = -1e30f;
#pragma unroll
            for (int t = 0; t < 9; ++t) m = fmaxf(m, acc[t][i]);
            if (v9) m = fmaxf(m, acc[9][i]);
#pragma unroll
            for (int off = 1; off < 16; off <<= 1) m = fmaxf(m, __shfl_xor(m, off));
            float s = 0.f;
#pragma unroll
            for (int t = 0; t < 10; ++t) {
                float e = 0.f;
                if (t < 9 || v9) e = __expf(0.125f * (acc[t][i] - m));
                s += e;
                pw[(ks * 4 + i) * VP + t * 16 + fr] = f2bf(e);
            }
#pragma unroll
            for (int off = 1; off < 16; off <<= 1) s += __shfl_xor(s, off);
            inv[i] = 1.f / s;
        }

        f32x4 o[4];
#pragma unroll
        for (int dt = 0; dt < 4; ++dt)
#pragma unroll
            for (int r = 0; r < 4; ++r) o[dt][r] = 0.f;
#pragma unroll
        for (int kc = 0; kc < 5; ++kc) {
            s16x8 pa = *(const s16x8*)(&pw[fr * VP + kc * 32 + ks * 8]);
#pragma unroll
            for (int dt = 0; dt < 4; ++dt) {
                s16x8 vb = *(const s16x8*)(&v_t[(dt * 16 + fr) * VP + kc * 32 + ks * 8]);
                o[dt] = __builtin_amdgcn_mfma_f32_16x16x32_bf16(pa, vb, o[dt], 0, 0, 0);
            }
        }

#pragma unroll
        for (int dt = 0; dt < 4; ++dt)
#pragma unroll
            for (int i = 0; i < 4; ++i) {
                const int q = qt * 16 + ks * 4 + i;
                if (q < 150) psum[dt] += o[dt][i] * inv[i];
            }
    }

#pragma unroll
    for (int dt = 0; dt < 4; ++dt) {
        float v = psum[dt];
        v += __shfl_xor(v, 16);
        v += __shfl_xor(v, 32);
        if (ks == 0) redsum[wid][dt * 16 + fr] = v;
    }
    __syncthreads();
    if (tid < 64) {
        const float s = redsum[0][tid] + redsum[1][tid] + redsum[2][tid] + redsum[3][tid];
        osum[(size_t)b * 512 + h * 64 + tid] = f2bf(s);
    }
}

// ---------------------------------------------------------------------------
extern "C" void kernel_launch(void* const* d_in, const int* in_sizes, int n_in,
                              void* d_out, int out_size, void* d_ws, size_t ws_size,
                              hipStream_t stream)
{
    (void)in_sizes; (void)n_in; (void)out_size; (void)ws_size;

    const int*   x          = (const int*)d_in[0];
    const float* emb        = (const float*)d_in[1];
    const float* W1         = (const float*)d_in[2];
    const float* b1         = (const float*)d_in[3];
    const float* ln1_g      = (const float*)d_in[4];
    const float* ln1_b      = (const float*)d_in[5];
    const float* W2         = (const float*)d_in[6];
    const float* b2         = (const float*)d_in[7];
    const float* dbias      = (const float*)d_in[8];
    const float* in_proj_w  = (const float*)d_in[9];
    const float* in_proj_b  = (const float*)d_in[10];
    const float* out_proj_w = (const float*)d_in[11];
    const float* out_proj_b = (const float*)d_in[12];
    const float* norm_g     = (const float*)d_in[13];
    const float* norm_b     = (const float*)d_in[14];
    const float* dec_w1     = (const float*)d_in[15];
    const float* dec_b1     = (const float*)d_in[16];
    const float* dec_w2     = (const float*)d_in[17];
    const float* dec_b2     = (const float*)d_in[18];

    char* ws = (char*)d_ws;
    unsigned short* e_bf  = (unsigned short*)(ws + 0x0);         // [256,512] bf16
    unsigned short* osum  = (unsigned short*)(ws + 0x40000);
    unsigned short* att1  = (unsigned short*)(ws + 0x80000);
    unsigned short* agg   = (unsigned short*)(ws + 0xC0000);
    unsigned short* dec1  = (unsigned short*)(ws + 0x100000);
    unsigned short* h1    = (unsigned short*)(ws + 0x200000);    // [B,M,D] 37.5MB
    unsigned short* mo    = (unsigned short*)(ws + 0x2800000);   // [B,M,D] 37.5MB
    unsigned short* qkvf  = (unsigned short*)(ws + 0x4E00000);   // [B,M,3D] 112.5MB
    unsigned short* Wbf1  = (unsigned short*)(ws + 0xBE80000);   // 78.6MB
    unsigned short* Wbf2  = (unsigned short*)(ws + 0x10980000);  // 78.6MB
    unsigned short* ipwbf = (unsigned short*)(ws + 0x15480000);  // 1.5MB
    unsigned short* opwbf = (unsigned short*)(ws + 0x15600000);  // 0.5MB
    unsigned short* dw1bf = (unsigned short*)(ws + 0x15700000);  // 0.25MB
    unsigned short* dw2bf = (unsigned short*)(ws + 0x15800000);  // 5MB
    float*          epart = (float*)(ws + 0x15D00000);           // [2048,512] f32 4MB

    // 1) prep: embed stage-A + cvt W1 + cvt small weights (one launch)
    prep_kernel<<<PREP_BLOCKS, 256, 0, stream>>>(
        x, emb, epart, W1, Wbf1, in_proj_w, ipwbf, out_proj_w, opwbf,
        dec_w1, dw1bf, dec_w2, dw2bf);

    // 1b) embed stage-B reduce -> e_bf
    embed_reduce_kernel<<<256, 512, 0, stream>>>(epart, e_bf);

    // 2) G1 (1200 gemm blocks) + fused cvt-W2 tail (2048 blocks)
    gemm_bf_kernel<512, false, false><<<1200 + 2048, 256, 0, stream>>>(
        e_bf, Wbf1, b1, nullptr, 1.f, h1,
        512, 4, 2, 1200,
        (size_t)0, 512, (size_t)512 * 512, 512, 512, 76800,
        W2, Wbf2, 150 * 512 * 512 / 8);

    // 3) LN(ln1_g, ln1_b) + ReLU, in-place on h1
    ln_kernel<true><<<38400, 256, 0, stream>>>(h1, ln1_g, ln1_b, h1, 150);

    // 4) G2: mo = h1 @ W2bf^T + b2 + dbias
    gemm_bf_kernel<512, false, false><<<1200, 256, 0, stream>>>(
        h1, Wbf2, b2, dbias, 1.f, mo,
        512, 4, 2, 1200,
        (size_t)512, 76800, (size_t)512 * 512, 512, 512, 76800,
        nullptr, nullptr, 0);

    // 5) qkv = mo @ in_proj^T + in_proj_b  (single launch, 3600 blocks)
    gemm_bf_kernel<512, false, false><<<3600, 256, 0, stream>>>(
        mo, ipwbf, in_proj_b, nullptr, 1.f, qkvf,
        1536, 12, 300, 3600,
        (size_t)0, 512, (size_t)0, 0, 0, 1536,
        nullptr, nullptr, 0);

    // 6) attention + fused mode-sum -> osum [256,512]
    attn_mfma_kernel<<<2048, 256, 0, stream>>>(qkvf, osum);

    // 7) attended_sum = osum @ out_proj^T + 150*out_proj_b
    gemm_bf_kernel<512, false, false><<<8, 256, 0, stream>>>(
        osum, opwbf, out_proj_b, nullptr, 150.f, att1,
        512, 4, 2, 8,
        (size_t)0, 512, (size_t)0, 0, 0, 512,
        nullptr, nullptr, 0);

    // 8) agg = LN(attended_sum; norm_g, norm_b)
    ln_kernel<false><<<256, 256, 0, stream>>>(att1, norm_g, norm_b, agg, 1);

    // 9) dec1 = ReLU(agg @ dec_w1^T + dec_b1)   [256,256]
    gemm_bf_kernel<512, true, false><<<4, 256, 0, stream>>>(
        agg, dw1bf, dec_b1, nullptr, 1.f, dec1,
        256, 2, 2, 4,
        (size_t)0, 512, (size_t)0, 0, 0, 256,
        nullptr, nullptr, 0);

    // 10) out = dec1 @ dec_w2^T + dec_b2   [256,10000] f32, K=256
    gemm_bf_kernel<256, false, true><<<158, 256, 0, stream>>>(
        dec1, dw2bf, dec_b2, nullptr, 1.f, d_out,
        10000, 79, 2, 158,
        (size_t)0, 256, (size_t)0, 0, 0, 10000,
        nullptr, nullptr, 0);
}